// Round 7
// baseline (243.566 us; speedup 1.0000x reference)
//
#include <hip/hip_runtime.h>
#include <hip/hip_fp16.h>

#define DIM 128
#define EPS 1e-5f
#define WPB 4            // waves per block
#define UF  8            // consecutive edges per quarter-wave per trip
                         // -> 32 edges / wave-trip, 8 gathers (8KB) in flight

// native clang ext-vectors: required by __builtin_nontemporal_load/store
typedef int   vint4   __attribute__((ext_vector_type(4)));
typedef float vfloat4 __attribute__((ext_vector_type(4)));
typedef float vfloat2 __attribute__((ext_vector_type(2)));

// ---------------------------------------------------------------------------
// Prep kernel (fused): convert x fp32 -> fp16; build CSR row_ptr from the
// sorted edge_row (thread e covers rows (row[e-1], row[e]]).
// ---------------------------------------------------------------------------
__global__ void prep_kernel(const float4* __restrict__ x4,
                            __half2* __restrict__ xh2,
                            const int* __restrict__ edge_row,
                            int* __restrict__ row_ptr,
                            int n4, int n_nodes, int n_edges)
{
    int i = blockIdx.x * blockDim.x + threadIdx.x;
    if (i < n4) {
        float4 v = x4[i];
        xh2[2 * i]     = __float22half2_rn(make_float2(v.x, v.y));
        xh2[2 * i + 1] = __float22half2_rn(make_float2(v.z, v.w));
    }
    if (i < n_edges) {
        int cur  = edge_row[i];
        int prev = (i == 0) ? -1 : edge_row[i - 1];
        for (int r = prev + 1; r <= cur; ++r) row_ptr[r] = i;
        if (i == n_edges - 1) {
            for (int r = cur + 1; r <= n_nodes; ++r) row_ptr[r] = n_edges;
        }
    }
}

// ---------------------------------------------------------------------------
// Main kernel: one wave per node, split into 4 quarter-waves.
//   q   = lane>>4 : this lane's edge sub-stream (8 consecutive edges/trip)
//   sub = lane&15 : dim group [sub*8, sub*8+8), gathered as half8 = 16B
// Per trip: 32 edges, 4 broadcast VMEM for edge data (int4/float4 nt-loads),
// 8 gather insts (1024B each), fully predicated (no serial tail).
// ---------------------------------------------------------------------------
__global__ __launch_bounds__(WPB * 64)
void gnn_fused_kernel(const uint4* __restrict__ xh16,   // fp16 x, 16B units
                      const int*   __restrict__ row_ptr,
                      const int*   __restrict__ edge_col,
                      const float* __restrict__ edge_val,
                      const float* __restrict__ gamma,
                      const float* __restrict__ beta,
                      float*       __restrict__ out,
                      int n_nodes, int n_edges)
{
    const int wave = threadIdx.x >> 6;
    const int lane = threadIdx.x & 63;
    const int q    = lane >> 4;
    const int sub  = lane & 15;
    const int node = blockIdx.x * WPB + wave;
    if (node >= n_nodes) return;

    const int start = row_ptr[node];
    const int end   = row_ptr[node + 1];
    const unsigned len = (unsigned)(end - start);

    float acc[8];
#pragma unroll
    for (int k = 0; k < 8; ++k) acc[k] = 0.f;

    const int ebase = start & ~3;                 // 16B-align edge vec loads
    const int emax  = n_edges - 4;
    for (int e0 = ebase; e0 < end; e0 += 4 * UF) {
        const int b0  = e0 + q * UF;              // this quarter's 8 edges
        const int b0c = min(b0, emax);            // clamp: stay in-array
        const int b1c = min(b0 + 4, emax);
        // read-once streams: non-temporal, don't evict gather lines from L2
        vint4   ca = __builtin_nontemporal_load((const vint4*)  (edge_col + b0c));
        vint4   cb = __builtin_nontemporal_load((const vint4*)  (edge_col + b1c));
        vfloat4 wa = __builtin_nontemporal_load((const vfloat4*)(edge_val + b0c));
        vfloat4 wb = __builtin_nontemporal_load((const vfloat4*)(edge_val + b1c));

        int   c[UF] = {ca.x, ca.y, ca.z, ca.w, cb.x, cb.y, cb.z, cb.w};
        float w[UF] = {wa.x, wa.y, wa.z, wa.w, wb.x, wb.y, wb.z, wb.w};

        const int off = b0 - start;               // may be <0 at head
#pragma unroll
        for (int u = 0; u < UF; ++u) {
            bool in = (unsigned)(off + u) < len;
            c[u] = in ? c[u] : 0;                 // masked -> hot row 0
            w[u] = in ? w[u] : 0.f;
        }

        uint4 v[UF];
#pragma unroll
        for (int u = 0; u < UF; ++u)
            v[u] = xh16[c[u] * (DIM / 8) + sub];  // 16B/lane gather

#pragma unroll
        for (int u = 0; u < UF; ++u) {
            const __half* hp = (const __half*)&v[u];
#pragma unroll
            for (int j = 0; j < 8; ++j)           // fp16 operand -> v_fma_mix
                acc[j] = fmaf(w[u], __half2float(hp[j]), acc[j]);
        }
    }

    // fold the 4 quarter-waves (disjoint edge subsets) into every lane
#pragma unroll
    for (int k = 0; k < 8; ++k) {
        acc[k] += __shfl_xor(acc[k], 16, 64);
        acc[k] += __shfl_xor(acc[k], 32, 64);
    }

    // residual from fp16 x
    uint4 xv = xh16[node * (DIM / 8) + sub];
    const __half* xp = (const __half*)&xv;
    float h[8];
#pragma unroll
    for (int j = 0; j < 8; ++j) h[j] = acc[j] + __half2float(xp[j]);

    // layernorm stats: per-lane over 8 dims, then butterfly over sub (1,2,4,8)
    float s = 0.f, sq = 0.f;
#pragma unroll
    for (int k = 0; k < 8; ++k) { s += h[k]; sq += h[k] * h[k]; }
#pragma unroll
    for (int off = 1; off <= 8; off <<= 1) {
        s  += __shfl_xor(s,  off, 64);
        sq += __shfl_xor(sq, off, 64);
    }
    const float mean = s * (1.0f / (float)DIM);
    const float var  = sq * (1.0f / (float)DIM) - mean * mean;
    const float rs   = rsqrtf(var + EPS);

    // lane (q,sub) writes dims sub*8 + 2q + {0,1} (512B contiguous per node)
    float hx = (q < 2) ? ((q == 0) ? h[0] : h[2]) : ((q == 2) ? h[4] : h[6]);
    float hy = (q < 2) ? ((q == 0) ? h[1] : h[3]) : ((q == 2) ? h[5] : h[7]);
    const int didx = sub * 4 + q;
    const float2 g = ((const float2*)gamma)[didx];
    const float2 b = ((const float2*)beta)[didx];
    vfloat2 o;
    o.x = (hx - mean) * rs * g.x + b.x;
    o.y = (hy - mean) * rs * g.y + b.y;
    __builtin_nontemporal_store(o, (vfloat2*)out + node * (DIM / 2) + didx);
}

extern "C" void kernel_launch(void* const* d_in, const int* in_sizes, int n_in,
                              void* d_out, int out_size, void* d_ws, size_t ws_size,
                              hipStream_t stream)
{
    const float* x        = (const float*)d_in[0];
    const int*   edge_row = (const int*)  d_in[1];
    const int*   edge_col = (const int*)  d_in[2];
    const float* edge_val = (const float*)d_in[3];
    const float* gamma    = (const float*)d_in[4];
    const float* beta     = (const float*)d_in[5];
    float*       out      = (float*)d_out;

    const int n_nodes = in_sizes[0] / DIM;   // 100000
    const int n_edges = in_sizes[1];         // 3200000
    const int n_elem  = in_sizes[0];         // N*DIM
    const int n4      = n_elem / 4;

    // workspace: [x_half: n_elem*2 B][row_ptr: (n_nodes+1)*4 B]
    __half2* xh2     = (__half2*)d_ws;
    int*     row_ptr = (int*)((char*)d_ws + (size_t)n_elem * sizeof(__half));

    int prep_threads = (n4 > n_edges) ? n4 : n_edges;
    prep_kernel<<<(prep_threads + 255) / 256, 256, 0, stream>>>(
        (const float4*)x, xh2, edge_row, row_ptr, n4, n_nodes, n_edges);

    const int blocks = (n_nodes + WPB - 1) / WPB;
    gnn_fused_kernel<<<blocks, WPB * 64, 0, stream>>>(
        (const uint4*)d_ws, row_ptr, edge_col, edge_val, gamma, beta, out,
        n_nodes, n_edges);
}

// Round 8
// 240.867 us; speedup vs baseline: 1.0112x; 1.0112x over previous
//
#include <hip/hip_runtime.h>
#include <hip/hip_fp16.h>

#define DIM 128
#define EPS 1e-5f
#define WPB 4            // waves per block
#define UF  4            // 4 edges per quarter-wave per trip -> 16 edges/trip

// native clang ext-vectors: required by __builtin_nontemporal_load/store
typedef int   vint4   __attribute__((ext_vector_type(4)));
typedef float vfloat4 __attribute__((ext_vector_type(4)));
typedef float vfloat2 __attribute__((ext_vector_type(2)));

// ---------------------------------------------------------------------------
// Prep kernel (fused): convert x fp32 -> fp16; build CSR row_ptr from the
// sorted edge_row (thread e covers rows (row[e-1], row[e]]).
// ---------------------------------------------------------------------------
__global__ void prep_kernel(const float4* __restrict__ x4,
                            __half2* __restrict__ xh2,
                            const int* __restrict__ edge_row,
                            int* __restrict__ row_ptr,
                            int n4, int n_nodes, int n_edges)
{
    int i = blockIdx.x * blockDim.x + threadIdx.x;
    if (i < n4) {
        float4 v = x4[i];
        xh2[2 * i]     = __float22half2_rn(make_float2(v.x, v.y));
        xh2[2 * i + 1] = __float22half2_rn(make_float2(v.z, v.w));
    }
    if (i < n_edges) {
        int cur  = edge_row[i];
        int prev = (i == 0) ? -1 : edge_row[i - 1];
        for (int r = prev + 1; r <= cur; ++r) row_ptr[r] = i;
        if (i == n_edges - 1) {
            for (int r = cur + 1; r <= n_nodes; ++r) row_ptr[r] = n_edges;
        }
    }
}

// ---------------------------------------------------------------------------
// Main kernel: one wave per node, split into 4 quarter-waves.
//   q   = lane>>4 : owns 4 consecutive edges per trip (base e0+4q)
//   sub = lane&15 : dim group [sub*8, sub*8+8), gathered as half8 = 16B
// Per trip: 16 edges, 2 nt VMEM for edge data (int4+float4), 4 gather insts
// (1024B each), fully predicated (no serial tail). R5 trip shape (best TLP)
// + R7 vector edge loads.
// ---------------------------------------------------------------------------
__global__ __launch_bounds__(WPB * 64)
void gnn_fused_kernel(const uint4* __restrict__ xh16,   // fp16 x, 16B units
                      const int*   __restrict__ row_ptr,
                      const int*   __restrict__ edge_col,
                      const float* __restrict__ edge_val,
                      const float* __restrict__ gamma,
                      const float* __restrict__ beta,
                      float*       __restrict__ out,
                      int n_nodes, int n_edges)
{
    const int wave = threadIdx.x >> 6;
    const int lane = threadIdx.x & 63;
    const int q    = lane >> 4;
    const int sub  = lane & 15;
    const int node = blockIdx.x * WPB + wave;
    if (node >= n_nodes) return;

    const int start = row_ptr[node];
    const int end   = row_ptr[node + 1];
    const unsigned len = (unsigned)(end - start);

    float acc[8];
#pragma unroll
    for (int k = 0; k < 8; ++k) acc[k] = 0.f;

    const int ebase = start & ~3;                 // 16B-align edge vec loads
    const int emax  = n_edges - 4;
    for (int e0 = ebase; e0 < end; e0 += 4 * UF) {
        const int b  = e0 + 4 * q;                // this quarter's 4 edges
        const int bc = min(b, emax);              // clamp: stay in-array
        // one int4 + one float4 nt-load fetch this quarter's edge data
        vint4   c4 = __builtin_nontemporal_load((const vint4*)  (edge_col + bc));
        vfloat4 w4 = __builtin_nontemporal_load((const vfloat4*)(edge_val + bc));

        int   c[UF] = {c4.x, c4.y, c4.z, c4.w};
        float w[UF] = {w4.x, w4.y, w4.z, w4.w};

        const int off = b - start;                // may be <0 at head (q=0)
#pragma unroll
        for (int u = 0; u < UF; ++u) {
            bool in = (unsigned)(off + u) < len;
            c[u] = in ? c[u] : 0;                 // masked -> hot row 0
            w[u] = in ? w[u] : 0.f;
        }

        uint4 v[UF];
#pragma unroll
        for (int u = 0; u < UF; ++u)
            v[u] = xh16[c[u] * (DIM / 8) + sub];  // 16B/lane gather

#pragma unroll
        for (int u = 0; u < UF; ++u) {
            const __half* hp = (const __half*)&v[u];
#pragma unroll
            for (int j = 0; j < 8; ++j)           // fp16 operand -> v_fma_mix
                acc[j] = fmaf(w[u], __half2float(hp[j]), acc[j]);
        }
    }

    // fold the 4 quarter-waves (disjoint edge subsets) into every lane
#pragma unroll
    for (int k = 0; k < 8; ++k) {
        acc[k] += __shfl_xor(acc[k], 16, 64);
        acc[k] += __shfl_xor(acc[k], 32, 64);
    }

    // residual from fp16 x
    uint4 xv = xh16[node * (DIM / 8) + sub];
    const __half* xp = (const __half*)&xv;
    float h[8];
#pragma unroll
    for (int j = 0; j < 8; ++j) h[j] = acc[j] + __half2float(xp[j]);

    // layernorm stats: per-lane over 8 dims, then butterfly over sub (1,2,4,8)
    float s = 0.f, sq = 0.f;
#pragma unroll
    for (int k = 0; k < 8; ++k) { s += h[k]; sq += h[k] * h[k]; }
#pragma unroll
    for (int off = 1; off <= 8; off <<= 1) {
        s  += __shfl_xor(s,  off, 64);
        sq += __shfl_xor(sq, off, 64);
    }
    const float mean = s * (1.0f / (float)DIM);
    const float var  = sq * (1.0f / (float)DIM) - mean * mean;
    const float rs   = rsqrtf(var + EPS);

    // lane (q,sub) writes dims sub*8 + 2q + {0,1} (512B contiguous per node)
    float hx = (q < 2) ? ((q == 0) ? h[0] : h[2]) : ((q == 2) ? h[4] : h[6]);
    float hy = (q < 2) ? ((q == 0) ? h[1] : h[3]) : ((q == 2) ? h[5] : h[7]);
    const int didx = sub * 4 + q;
    const float2 g = ((const float2*)gamma)[didx];
    const float2 b = ((const float2*)beta)[didx];
    vfloat2 o;
    o.x = (hx - mean) * rs * g.x + b.x;
    o.y = (hy - mean) * rs * g.y + b.y;
    __builtin_nontemporal_store(o, (vfloat2*)out + node * (DIM / 2) + didx);
}

extern "C" void kernel_launch(void* const* d_in, const int* in_sizes, int n_in,
                              void* d_out, int out_size, void* d_ws, size_t ws_size,
                              hipStream_t stream)
{
    const float* x        = (const float*)d_in[0];
    const int*   edge_row = (const int*)  d_in[1];
    const int*   edge_col = (const int*)  d_in[2];
    const float* edge_val = (const float*)d_in[3];
    const float* gamma    = (const float*)d_in[4];
    const float* beta     = (const float*)d_in[5];
    float*       out      = (float*)d_out;

    const int n_nodes = in_sizes[0] / DIM;   // 100000
    const int n_edges = in_sizes[1];         // 3200000
    const int n_elem  = in_sizes[0];         // N*DIM
    const int n4      = n_elem / 4;

    // workspace: [x_half: n_elem*2 B][row_ptr: (n_nodes+1)*4 B]
    __half2* xh2     = (__half2*)d_ws;
    int*     row_ptr = (int*)((char*)d_ws + (size_t)n_elem * sizeof(__half));

    int prep_threads = (n4 > n_edges) ? n4 : n_edges;
    prep_kernel<<<(prep_threads + 255) / 256, 256, 0, stream>>>(
        (const float4*)x, xh2, edge_row, row_ptr, n4, n_nodes, n_edges);

    const int blocks = (n_nodes + WPB - 1) / WPB;
    gnn_fused_kernel<<<blocks, WPB * 64, 0, stream>>>(
        (const uint4*)d_ws, row_ptr, edge_col, edge_val, gamma, beta, out,
        n_nodes, n_edges);
}

// Round 9
// 235.532 us; speedup vs baseline: 1.0341x; 1.0227x over previous
//
#include <hip/hip_runtime.h>
#include <hip/hip_fp16.h>

#define DIM 128
#define EPS 1e-5f
#define WPB 4            // waves per block
#define UF  4            // 4 edges per quarter-wave per trip -> 16 edges/trip

// native clang ext-vectors (needed for __builtin_nontemporal_store)
typedef float vfloat2 __attribute__((ext_vector_type(2)));

// ---------------------------------------------------------------------------
// Prep kernel (fused): convert x fp32 -> fp16; build CSR row_ptr from the
// sorted edge_row (thread e covers rows (row[e-1], row[e]]).
// ---------------------------------------------------------------------------
__global__ void prep_kernel(const float4* __restrict__ x4,
                            __half2* __restrict__ xh2,
                            const int* __restrict__ edge_row,
                            int* __restrict__ row_ptr,
                            int n4, int n_nodes, int n_edges)
{
    int i = blockIdx.x * blockDim.x + threadIdx.x;
    if (i < n4) {
        float4 v = x4[i];
        xh2[2 * i]     = __float22half2_rn(make_float2(v.x, v.y));
        xh2[2 * i + 1] = __float22half2_rn(make_float2(v.z, v.w));
    }
    if (i < n_edges) {
        int cur  = edge_row[i];
        int prev = (i == 0) ? -1 : edge_row[i - 1];
        for (int r = prev + 1; r <= cur; ++r) row_ptr[r] = i;
        if (i == n_edges - 1) {
            for (int r = cur + 1; r <= n_nodes; ++r) row_ptr[r] = n_edges;
        }
    }
}

// ---------------------------------------------------------------------------
// Main kernel: one wave per node, split into 4 quarter-waves.
//   q   = lane>>4 : owns 4 consecutive edges per trip (base e0+4q)
//   sub = lane&15 : dim group [sub*8, sub*8+8), gathered as half8 = 16B
// Per trip: 16 edges, 2 cached vector VMEM for edge data (int4+float4 —
// NOT non-temporal: R8 showed nt evicts boundary lines shared by adjacent
// nodes, +14MB FETCH), 4 gather insts (1024B each), fully predicated.
// ---------------------------------------------------------------------------
__global__ __launch_bounds__(WPB * 64)
void gnn_fused_kernel(const uint4* __restrict__ xh16,   // fp16 x, 16B units
                      const int*   __restrict__ row_ptr,
                      const int*   __restrict__ edge_col,
                      const float* __restrict__ edge_val,
                      const float* __restrict__ gamma,
                      const float* __restrict__ beta,
                      float*       __restrict__ out,
                      int n_nodes, int n_edges)
{
    const int wave = threadIdx.x >> 6;
    const int lane = threadIdx.x & 63;
    const int q    = lane >> 4;
    const int sub  = lane & 15;
    const int node = blockIdx.x * WPB + wave;
    if (node >= n_nodes) return;

    const int start = row_ptr[node];
    const int end   = row_ptr[node + 1];
    const unsigned len = (unsigned)(end - start);

    float acc[8];
#pragma unroll
    for (int k = 0; k < 8; ++k) acc[k] = 0.f;

    const int ebase = start & ~3;                 // 16B-align edge vec loads
    const int emax  = n_edges - 4;
    for (int e0 = ebase; e0 < end; e0 += 4 * UF) {
        const int b  = e0 + 4 * q;                // this quarter's 4 edges
        const int bc = min(b, emax);              // clamp: stay in-array
        // cached (L2-retained) vector loads of this quarter's edge data
        int4   c4 = *(const int4*)  (edge_col + bc);
        float4 w4 = *(const float4*)(edge_val + bc);

        int   c[UF] = {c4.x, c4.y, c4.z, c4.w};
        float w[UF] = {w4.x, w4.y, w4.z, w4.w};

        const int off = b - start;                // may be <0 at head (q=0)
#pragma unroll
        for (int u = 0; u < UF; ++u) {
            bool in = (unsigned)(off + u) < len;
            c[u] = in ? c[u] : 0;                 // masked -> hot row 0
            w[u] = in ? w[u] : 0.f;
        }

        uint4 v[UF];
#pragma unroll
        for (int u = 0; u < UF; ++u)
            v[u] = xh16[c[u] * (DIM / 8) + sub];  // 16B/lane gather

#pragma unroll
        for (int u = 0; u < UF; ++u) {
            const __half* hp = (const __half*)&v[u];
#pragma unroll
            for (int j = 0; j < 8; ++j)           // fp16 operand -> v_fma_mix
                acc[j] = fmaf(w[u], __half2float(hp[j]), acc[j]);
        }
    }

    // fold the 4 quarter-waves (disjoint edge subsets) into every lane
#pragma unroll
    for (int k = 0; k < 8; ++k) {
        acc[k] += __shfl_xor(acc[k], 16, 64);
        acc[k] += __shfl_xor(acc[k], 32, 64);
    }

    // residual from fp16 x
    uint4 xv = xh16[node * (DIM / 8) + sub];
    const __half* xp = (const __half*)&xv;
    float h[8];
#pragma unroll
    for (int j = 0; j < 8; ++j) h[j] = acc[j] + __half2float(xp[j]);

    // layernorm stats: per-lane over 8 dims, then butterfly over sub (1,2,4,8)
    float s = 0.f, sq = 0.f;
#pragma unroll
    for (int k = 0; k < 8; ++k) { s += h[k]; sq += h[k] * h[k]; }
#pragma unroll
    for (int off = 1; off <= 8; off <<= 1) {
        s  += __shfl_xor(s,  off, 64);
        sq += __shfl_xor(sq, off, 64);
    }
    const float mean = s * (1.0f / (float)DIM);
    const float var  = sq * (1.0f / (float)DIM) - mean * mean;
    const float rs   = rsqrtf(var + EPS);

    // lane (q,sub) writes dims sub*8 + 2q + {0,1} (512B contiguous per node)
    float hx = (q < 2) ? ((q == 0) ? h[0] : h[2]) : ((q == 2) ? h[4] : h[6]);
    float hy = (q < 2) ? ((q == 0) ? h[1] : h[3]) : ((q == 2) ? h[5] : h[7]);
    const int didx = sub * 4 + q;
    const float2 g = ((const float2*)gamma)[didx];
    const float2 b = ((const float2*)beta)[didx];
    vfloat2 o;
    o.x = (hx - mean) * rs * g.x + b.x;
    o.y = (hy - mean) * rs * g.y + b.y;
    __builtin_nontemporal_store(o, (vfloat2*)out + node * (DIM / 2) + didx);
}

extern "C" void kernel_launch(void* const* d_in, const int* in_sizes, int n_in,
                              void* d_out, int out_size, void* d_ws, size_t ws_size,
                              hipStream_t stream)
{
    const float* x        = (const float*)d_in[0];
    const int*   edge_row = (const int*)  d_in[1];
    const int*   edge_col = (const int*)  d_in[2];
    const float* edge_val = (const float*)d_in[3];
    const float* gamma    = (const float*)d_in[4];
    const float* beta     = (const float*)d_in[5];
    float*       out      = (float*)d_out;

    const int n_nodes = in_sizes[0] / DIM;   // 100000
    const int n_edges = in_sizes[1];         // 3200000
    const int n_elem  = in_sizes[0];         // N*DIM
    const int n4      = n_elem / 4;

    // workspace: [x_half: n_elem*2 B][row_ptr: (n_nodes+1)*4 B]
    __half2* xh2     = (__half2*)d_ws;
    int*     row_ptr = (int*)((char*)d_ws + (size_t)n_elem * sizeof(__half));

    int prep_threads = (n4 > n_edges) ? n4 : n_edges;
    prep_kernel<<<(prep_threads + 255) / 256, 256, 0, stream>>>(
        (const float4*)x, xh2, edge_row, row_ptr, n4, n_nodes, n_edges);

    const int blocks = (n_nodes + WPB - 1) / WPB;
    gnn_fused_kernel<<<blocks, WPB * 64, 0, stream>>>(
        (const uint4*)d_ws, row_ptr, edge_col, edge_val, gamma, beta, out,
        n_nodes, n_edges);
}